// Round 9
// baseline (180.916 us; speedup 1.0000x reference)
//
#include <hip/hip_runtime.h>
#include <cstdint>
#include <math.h>

// Problem constants (from reference)
constexpr int B = 32;
constexpr int M = 5120;          // 32*32*5 anchors
constexpr int C = 80;            // classes
constexpr int K = 1000;          // TOPK
constexpr float NMS_T  = 0.6f;

// d_out layout (flat float32, return order): scores | labels | bboxes | keep
constexpr int OFF_SCORE = 0;
constexpr int OFF_LAB   = B * K;            // 32000
constexpr int OFF_BOX   = 2 * B * K;        // 64000
constexpr int OFF_KEEP  = 2 * B * K + 4 * B * K; // 192000

// workspace layout (bytes)
constexpr size_t WS_KEYS     = 0;                                   // B*M u64
constexpr size_t WS_LABELS   = WS_KEYS   + (size_t)B * M * 8;       // B*M int
constexpr size_t WS_SELSC    = WS_LABELS + (size_t)B * M * 4;       // B*K f32
constexpr size_t WS_BOXOFF   = WS_SELSC + (size_t)B * K * 4;        // B*K*4 f32
constexpr size_t WS_MASK     = WS_BOXOFF + (size_t)B * K * 4 * 4;   // B*K*16 u64

// Correctly-rounded f32 exp: compute in f64 (ocml exp), round once. Verified
// bit-exact vs the harness's np reference (R4 absmax 0.0) — do not change.
__device__ __forceinline__ float expf_cr(float x) {
    return (float)exp((double)x);
}
// numpy-style f32 sigmoid: 1/(1+exp(-x)), every op in f32, no contraction.
__device__ __forceinline__ float sigm_np(float x) {
    float e = expf_cr(-x);
    return __fdiv_rn(1.0f, __fadd_rn(1.0f, e));
}

// Kernel 1: numpy-f32 score/label — 8 LANES PER ANCHOR for occupancy.
// Lane j of each 8-lane group owns classes {j, j+8, ..., j+72} = numpy's
// pairwise-sum column j. Column accumulation is sequential in k (numpy's
// order); the cross-lane shfl_xor(1,2,4) add tree reproduces numpy's
// ((r0+r1)+(r2+r3))+((r4+r5)+(r6+r7)) bitwise (IEEE add commutes exactly).
// max / first-argmax are order-invariant lattice ops (tie -> smaller index).
// Every f32 op is identical to the verified R4 kernel -> outputs bit-equal.
// VGPR ~35 (was ~110 with ev[80]) -> 8 waves/SIMD; 5120 blocks.
__global__ void __launch_bounds__(256)
k_scores(const float* __restrict__ conf, const float* __restrict__ cls,
         unsigned long long* __restrict__ keys, int* __restrict__ labels) {
    int b = blockIdx.y;                  // 0..31
    int g0 = blockIdx.x * 32;            // anchor base within batch (grid.x=160)
    int tid = threadIdx.x;               // 0..255 -> 32 anchors x 8 lanes
    __shared__ float s_lds[32];
    if (tid < 32) {                      // batch the 32 sigmoids (1 wave-exp)
        s_lds[tid] = sigm_np(conf[(size_t)b * M + g0 + tid]);
    }
    __syncthreads();
    int grp = tid >> 3;                  // anchor within block (0..31)
    int j   = tid & 7;                   // numpy column (0..7)
    int m = g0 + grp;
    size_t base = ((size_t)b * M + m) * C + j;
    float x[10];
#pragma unroll
    for (int k = 0; k < 10; k++) x[k] = cls[base + 8 * k];
    // row max (order-invariant)
    float mx = x[0];
#pragma unroll
    for (int k = 1; k < 10; k++) mx = fmaxf(mx, x[k]);
#pragma unroll
    for (int d = 1; d < 8; d <<= 1) mx = fmaxf(mx, __shfl_xor(mx, d, 64));
    // e_c = CR exp(f32(x - mx)); column sum in numpy's sequential order
    float e[10];
#pragma unroll
    for (int k = 0; k < 10; k++) e[k] = expf_cr(__fsub_rn(x[k], mx));
    float r = e[0];
#pragma unroll
    for (int k = 1; k < 10; k++) r = __fadd_rn(r, e[k]);
    // numpy tree combine across the 8 columns (bitwise-exact)
    float t1  = __fadd_rn(r,  __shfl_xor(r, 1, 64));
    float t2  = __fadd_rn(t1, __shfl_xor(t1, 2, 64));
    float sum = __fadd_rn(t2, __shfl_xor(t2, 4, 64));
    float s = s_lds[grp];
    // products p_c = f32(s * f32(e_c / sum)); first-argmax + max value
    float best = -1.0f; int bc = 0;
#pragma unroll
    for (int k = 0; k < 10; k++) {
        float q = __fdiv_rn(e[k], sum);
        float p = __fmul_rn(s, q);
        if (p > best) { best = p; bc = 8 * k + j; }   // k asc => first max
    }
#pragma unroll
    for (int d = 1; d < 8; d <<= 1) {    // lattice max on (p, -c): any order
        float op = __shfl_xor(best, d, 64);
        int   oc = __shfl_xor(bc,   d, 64);
        if (op > best || (op == best && oc < bc)) { best = op; bc = oc; }
    }
    if (j == 0) {
        keys[(size_t)b * M + m] =
            ((unsigned long long)__float_as_uint(best) << 32) |
            (unsigned long long)(0xFFFFFFFFu - (unsigned)m);
        labels[(size_t)b * M + m] = bc;
    }
}

// Decode one selected box (numpy-f32 op order) and write all its outputs.
__device__ __forceinline__ void decode_write(
    int b, int rank, int m, float score, int lab,
    const float* __restrict__ reg, const float* __restrict__ anchors,
    float* __restrict__ out, float4* __restrict__ boxes_off,
    float* __restrict__ sel_score)
{
    float4 r = ((const float4*)reg)[(size_t)b * M + m];
    float4 a = ((const float4*)anchors)[m];
    float cx = __fadd_rn(__fmul_rn(sigm_np(r.x), 16.0f), a.x);
    float cy = __fadd_rn(__fmul_rn(sigm_np(r.y), 16.0f), a.y);
    float w  = __fmul_rn(expf_cr(r.z), a.z);
    float h  = __fmul_rn(expf_cr(r.w), a.w);
    float x1 = __fdiv_rn(__fsub_rn(cx, __fmul_rn(0.5f, w)), 512.0f);
    float y1 = __fdiv_rn(__fsub_rn(cy, __fmul_rn(0.5f, h)), 512.0f);
    float x2 = __fdiv_rn(__fadd_rn(cx, __fmul_rn(0.5f, w)), 512.0f);
    float y2 = __fdiv_rn(__fadd_rn(cy, __fmul_rn(0.5f, h)), 512.0f);
    x1 = fminf(fmaxf(x1, 0.0f), 1.0f);
    y1 = fminf(fmaxf(y1, 0.0f), 1.0f);
    x2 = fminf(fmaxf(x2, 0.0f), 1.0f);
    y2 = fminf(fmaxf(y2, 0.0f), 1.0f);
    ((float4*)(out + OFF_BOX))[b * K + rank] = make_float4(x1, y1, x2, y2);
    out[OFF_LAB + b * K + rank] = (float)lab;
    float off = __fmul_rn(2.0f, (float)lab);
    boxes_off[b * K + rank] = make_float4(__fadd_rn(x1, off), __fadd_rn(y1, off),
                                          __fadd_rn(x2, off), __fadd_rn(y2, off));
    sel_score[b * K + rank] = score;
}

// Kernel 2: exact top-K via histogram-select + RANK-SCAN, one block/batch.
// Candidates (bins >= threshold bin, S ~= K+300) compacted to LDS; each
// thread ranks its candidate(s) by counting strictly-greater keys over the
// S candidates (unique keys -> distinct ranks; winners' candidate-rank ==
// global rank since every greater key is also a candidate). No sort, no
// per-stage barriers. Exact O(M^2) fallback on overflow (>2048).
__global__ void __launch_bounds__(1024)
k_topk(const unsigned long long* __restrict__ keys,
       const int* __restrict__ labels,
       const float* __restrict__ reg, const float* __restrict__ anchors,
       float* __restrict__ out, float4* __restrict__ boxes_off,
       float* __restrict__ sel_score) {
    int b = blockIdx.x;                  // grid = 32
    int tid = threadIdx.x;               // block = 1024
    const unsigned long long* kb = keys + (size_t)b * M;

    __shared__ unsigned int hist[2048];
    __shared__ unsigned int sufA[2048];
    __shared__ unsigned int sufB[2048];
    __shared__ unsigned long long cand[2048];   // 16 KB
    __shared__ int scnt, thrBin, ovf;

    for (int i = tid; i < 2048; i += 1024) hist[i] = 0;
    if (tid == 0) { scnt = 0; ovf = 0; }
    __syncthreads();

    unsigned long long k5[5];
#pragma unroll
    for (int i = 0; i < 5; i++) {
        k5[i] = kb[tid + i * 1024];              // coalesced
        atomicAdd(&hist[(unsigned)(k5[i] >> 51)], 1u);
    }
    __syncthreads();
    // Hillis-Steele suffix scan over 2048 bins (11 steps, ping-pong)
    for (int i = tid; i < 2048; i += 1024) sufA[i] = hist[i];
    __syncthreads();
    unsigned int* src = sufA; unsigned int* dst = sufB;
    for (int d = 1; d < 2048; d <<= 1) {
        for (int i = tid; i < 2048; i += 1024) {
            unsigned int v = src[i];
            if (i + d < 2048) v += src[i + d];
            dst[i] = v;
        }
        __syncthreads();
        unsigned int* tmp = src; src = dst; dst = tmp;
    }
    // threshold bin: unique crossing point of the non-increasing suffix counts
    for (int i = tid; i < 2048; i += 1024) {
        unsigned int s = src[i];
        unsigned int sn = (i + 1 < 2048) ? src[i + 1] : 0u;
        if (s >= (unsigned)K && sn < (unsigned)K) thrBin = i;
    }
    __syncthreads();
    int T = thrBin;
#pragma unroll
    for (int i = 0; i < 5; i++) {
        if ((int)(k5[i] >> 51) >= T) {
            int pos = atomicAdd(&scnt, 1);
            if (pos < 2048) cand[pos] = k5[i]; else ovf = 1;
        }
    }
    __syncthreads();
    if (!ovf) {
        int S = scnt;                            // <= 2048, typically ~1005
        for (int i = tid; i < S; i += 1024) {
            unsigned long long key = cand[i];
            int rank = 0;
#pragma unroll 4
            for (int x = 0; x < S; x++)
                rank += (cand[x] > key) ? 1 : 0; // LDS broadcast (uniform x)
            if (rank < K) {
                int mm = (int)(0xFFFFFFFFu - (unsigned)(key & 0xFFFFFFFFu));
                float sc = __uint_as_float((unsigned)(key >> 32));
                int lab = labels[(size_t)b * M + mm];
                decode_write(b, rank, mm, sc, lab, reg, anchors, out, boxes_off, sel_score);
            }
        }
    } else {
        // exact fallback (never expected for this data): O(M) rank per key
#pragma unroll
        for (int i = 0; i < 5; i++) {
            unsigned long long my = k5[i];
            int rank = 0;
            for (int j = 0; j < M; j++) rank += (kb[j] > my) ? 1 : 0;
            if (rank < K) {
                int mm = tid + i * 1024;
                float sc = __uint_as_float((unsigned)(my >> 32));
                int lab = labels[(size_t)b * M + mm];
                decode_write(b, rank, mm, sc, lab, reg, anchors, out, boxes_off, sel_score);
            }
        }
    }
}

// Kernel 3: suppression bitmask, occupancy-tiled + lower-triangle only.
// (word W of row i needed by k_nms iff W <= i>>6 == rowTile; IoU math f32,
// reference op order -> consumed bits bit-identical.)
__global__ void __launch_bounds__(256)
k_mask(const float4* __restrict__ boxes_off,
       unsigned long long* __restrict__ mask) {
    int b = blockIdx.z;
    int rowTile = blockIdx.x;            // 0..15
    int wgGroup = blockIdx.y;            // 0..3
    if (4 * wgGroup > rowTile) return;   // block-uniform: no needed words
    int tid = threadIdx.x;               // 0..255
    __shared__ float4 sbj[256];
    __shared__ float  saj[256];
    __shared__ float4 sbi[64];
    __shared__ float  sai[64];
    int j = wgGroup * 256 + tid;
    float4 bx = (j < K) ? boxes_off[b * K + j]
                        : make_float4(3e30f, 3e30f, -3e30f, -3e30f);
    sbj[tid] = bx;
    saj[tid] = __fmul_rn(__fsub_rn(bx.z, bx.x), __fsub_rn(bx.w, bx.y));
    if (tid < 64) {
        int i = rowTile * 64 + tid;
        float4 bv = (i < K) ? boxes_off[b * K + i] : make_float4(0, 0, 0, 0);
        sbi[tid] = bv;
        sai[tid] = __fmul_rn(__fsub_rn(bv.z, bv.x), __fsub_rn(bv.w, bv.y));
    }
    __syncthreads();
    int r  = tid & 63;                   // row within tile (lane)
    int wg = tid >> 6;                   // word within group (wave index)
    int W  = wgGroup * 4 + wg;           // global word index (wave-uniform)
    if (W > rowTile) return;             // whole-wave exit, after the barrier
    int i = rowTile * 64 + r;
    if (i >= K) return;
    float4 bi = sbi[r];
    float ai = sai[r];
    unsigned long long bits = 0ull;
    int base = wg * 64;
#pragma unroll 8
    for (int jj = 0; jj < 64; jj++) {
        float4 bj = sbj[base + jj];      // wave-uniform -> broadcast
        float xx1 = fmaxf(bi.x, bj.x), yy1 = fmaxf(bi.y, bj.y);
        float xx2 = fminf(bi.z, bj.z), yy2 = fminf(bi.w, bj.w);
        float ww = fmaxf(1e-28f, __fsub_rn(xx2, xx1));
        float hh = fmaxf(1e-28f, __fsub_rn(yy2, yy1));
        float inter = __fmul_rn(ww, hh);
        float denom = __fadd_rn(__fsub_rn(__fadd_rn(ai, saj[base + jj]), inter), 1e-14f);
        float iou = __fdiv_rn(inter, denom);
        if (iou > NMS_T) bits |= (1ull << jj);
    }
    mask[((size_t)b * K + i) * 16 + W] = bits;
}

// Kernel 4: exact NMS via bracketed Jacobi fixed point (see R5 notes).
__global__ void __launch_bounds__(1024)
k_nms(const unsigned long long* __restrict__ mask,
      const float* __restrict__ sel_score,
      float* __restrict__ out) {
    int b = blockIdx.x;
    int j = threadIdx.x;                 // 0..1023
    int w = j >> 6;                      // wave index == keep-word index
    int jb = j & 63;
    __shared__ unsigned long long U[16], L[16];
    __shared__ int flag[2];
    unsigned long long rw[16];
    if (j < K) {
        const ulonglong2* rp2 =
            (const ulonglong2*)(mask + ((size_t)b * K + j) * 16);
#pragma unroll
        for (int t = 0; t < 8; t++) {
            ulonglong2 v = rp2[t];
            rw[2 * t] = v.x; rw[2 * t + 1] = v.y;
        }
#pragma unroll
        for (int t = 0; t < 16; t++) {
            unsigned long long bm =
                (t < w) ? ~0ull
                        : ((t == w && jb != 0) ? ((1ull << jb) - 1ull) : 0ull);
            rw[t] &= bm;                 // only i<j can suppress j
        }
    } else {
#pragma unroll
        for (int t = 0; t < 16; t++) rw[t] = 0ull;
    }
    if (j < 16) { U[j] = (j < 15) ? ~0ull : ((1ull << 40) - 1); L[j] = 0ull; }
    if (j == 0) { flag[0] = 0; flag[1] = 0; }
    __syncthreads();
    for (int k = 0; k < 1025; k++) {
        unsigned long long supU = 0ull, supL = 0ull;
#pragma unroll
        for (int t = 0; t < 16; t++) {
            unsigned long long Ut = U[t], Lt = L[t];   // broadcast (same addr)
            supU |= Lt & rw[t];   // new U = f(L)
            supL |= Ut & rw[t];   // new L = f(U)
        }
        bool nu = (j < K) && (supU == 0ull);
        bool nl = (j < K) && (supL == 0ull);
        __syncthreads();                     // all reads of old U/L done
        unsigned long long bu = __ballot(nu);
        unsigned long long bl = __ballot(nl);
        if (jb == 0) {
            U[w] = bu; L[w] = bl;
            if (bu != bl) flag[k & 1] = 1;
        }
        if (j == 0) flag[(k + 1) & 1] = 0;
        __syncthreads();
        if (flag[k & 1] == 0) break;         // uniform exit; U==L == exact keep
    }
    if (j < K) {
        bool kp = ((U[w] >> jb) & 1ull) != 0ull;
        float s = sel_score[b * K + j];
        kp = kp && (s >= 0.05f);
        out[OFF_SCORE + b * K + j] = kp ? s : 0.0f;
        out[OFF_KEEP + b * K + j]  = kp ? 1.0f : 0.0f;
    }
}

extern "C" void kernel_launch(void* const* d_in, const int* in_sizes, int n_in,
                              void* d_out, int out_size, void* d_ws, size_t ws_size,
                              hipStream_t stream) {
    const float* conf    = (const float*)d_in[0];
    const float* cls     = (const float*)d_in[1];
    const float* reg     = (const float*)d_in[2];
    const float* anchors = (const float*)d_in[3];
    float* out = (float*)d_out;
    char* ws = (char*)d_ws;

    unsigned long long* keys = (unsigned long long*)(ws + WS_KEYS);
    int*    labels   = (int*)(ws + WS_LABELS);
    float*  sel_sc   = (float*)(ws + WS_SELSC);
    float4* boxes_off = (float4*)(ws + WS_BOXOFF);
    unsigned long long* mask = (unsigned long long*)(ws + WS_MASK);

    k_scores<<<dim3(160, B), 256, 0, stream>>>(conf, cls, keys, labels);
    k_topk  <<<B, 1024, 0, stream>>>(keys, labels, reg, anchors, out, boxes_off, sel_sc);
    k_mask  <<<dim3(16, 4, B), 256, 0, stream>>>(boxes_off, mask);
    k_nms   <<<32, 1024, 0, stream>>>(mask, sel_sc, out);
}

// Round 10
// 159.691 us; speedup vs baseline: 1.1329x; 1.1329x over previous
//
#include <hip/hip_runtime.h>
#include <cstdint>
#include <math.h>

// Problem constants (from reference)
constexpr int B = 32;
constexpr int M = 5120;          // 32*32*5 anchors
constexpr int C = 80;            // classes
constexpr int K = 1000;          // TOPK
constexpr float NMS_T  = 0.6f;

// d_out layout (flat float32, return order): scores | labels | bboxes | keep
constexpr int OFF_SCORE = 0;
constexpr int OFF_LAB   = B * K;            // 32000
constexpr int OFF_BOX   = 2 * B * K;        // 64000
constexpr int OFF_KEEP  = 2 * B * K + 4 * B * K; // 192000

// workspace layout (bytes)
constexpr size_t WS_KEYS     = 0;                                   // B*M u64
constexpr size_t WS_LABELS   = WS_KEYS   + (size_t)B * M * 8;       // B*M int
constexpr size_t WS_SELSC    = WS_LABELS + (size_t)B * M * 4;       // B*K f32
constexpr size_t WS_BOXOFF   = WS_SELSC + (size_t)B * K * 4;        // B*K*4 f32
constexpr size_t WS_MASK     = WS_BOXOFF + (size_t)B * K * 4 * 4;   // B*K*16 u64

// Correctly-rounded f32 exp: compute in f64 (ocml exp), round once. Verified
// bit-exact vs the harness's np reference (R4 absmax 0.0) — do not change.
__device__ __forceinline__ float expf_cr(float x) {
    return (float)exp((double)x);
}
// numpy-style f32 sigmoid: 1/(1+exp(-x)), every op in f32, no contraction.
__device__ __forceinline__ float sigm_np(float x) {
    float e = expf_cr(-x);
    return __fdiv_rn(1.0f, __fadd_rn(1.0f, e));
}

// Kernel 1: numpy-f32 score/label — 8 lanes per anchor (R9, kept: ~16 µs win).
// Lane j owns numpy pairwise-sum column j (classes j, j+8, ..., j+72);
// shfl_xor(1,2,4) add tree == numpy's tree combine bitwise. max/first-argmax
// are order-invariant lattice ops. All f32 ops identical to verified R4.
__global__ void __launch_bounds__(256)
k_scores(const float* __restrict__ conf, const float* __restrict__ cls,
         unsigned long long* __restrict__ keys, int* __restrict__ labels) {
    int b = blockIdx.y;                  // 0..31
    int g0 = blockIdx.x * 32;            // anchor base within batch (grid.x=160)
    int tid = threadIdx.x;               // 0..255 -> 32 anchors x 8 lanes
    __shared__ float s_lds[32];
    if (tid < 32) {                      // batch the 32 sigmoids (1 wave-exp)
        s_lds[tid] = sigm_np(conf[(size_t)b * M + g0 + tid]);
    }
    __syncthreads();
    int grp = tid >> 3;                  // anchor within block (0..31)
    int j   = tid & 7;                   // numpy column (0..7)
    int m = g0 + grp;
    size_t base = ((size_t)b * M + m) * C + j;
    float x[10];
#pragma unroll
    for (int k = 0; k < 10; k++) x[k] = cls[base + 8 * k];
    float mx = x[0];
#pragma unroll
    for (int k = 1; k < 10; k++) mx = fmaxf(mx, x[k]);
#pragma unroll
    for (int d = 1; d < 8; d <<= 1) mx = fmaxf(mx, __shfl_xor(mx, d, 64));
    float e[10];
#pragma unroll
    for (int k = 0; k < 10; k++) e[k] = expf_cr(__fsub_rn(x[k], mx));
    float r = e[0];
#pragma unroll
    for (int k = 1; k < 10; k++) r = __fadd_rn(r, e[k]);
    float t1  = __fadd_rn(r,  __shfl_xor(r, 1, 64));
    float t2  = __fadd_rn(t1, __shfl_xor(t1, 2, 64));
    float sum = __fadd_rn(t2, __shfl_xor(t2, 4, 64));
    float s = s_lds[grp];
    float best = -1.0f; int bc = 0;
#pragma unroll
    for (int k = 0; k < 10; k++) {
        float q = __fdiv_rn(e[k], sum);
        float p = __fmul_rn(s, q);
        if (p > best) { best = p; bc = 8 * k + j; }   // k asc => first max
    }
#pragma unroll
    for (int d = 1; d < 8; d <<= 1) {    // lattice max on (p, -c): any order
        float op = __shfl_xor(best, d, 64);
        int   oc = __shfl_xor(bc,   d, 64);
        if (op > best || (op == best && oc < bc)) { best = op; bc = oc; }
    }
    if (j == 0) {
        keys[(size_t)b * M + m] =
            ((unsigned long long)__float_as_uint(best) << 32) |
            (unsigned long long)(0xFFFFFFFFu - (unsigned)m);
        labels[(size_t)b * M + m] = bc;
    }
}

// Decode one selected box (numpy-f32 op order) and write all its outputs.
__device__ __forceinline__ void decode_write(
    int b, int rank, int m, float score, int lab,
    const float* __restrict__ reg, const float* __restrict__ anchors,
    float* __restrict__ out, float4* __restrict__ boxes_off,
    float* __restrict__ sel_score)
{
    float4 r = ((const float4*)reg)[(size_t)b * M + m];
    float4 a = ((const float4*)anchors)[m];
    float cx = __fadd_rn(__fmul_rn(sigm_np(r.x), 16.0f), a.x);
    float cy = __fadd_rn(__fmul_rn(sigm_np(r.y), 16.0f), a.y);
    float w  = __fmul_rn(expf_cr(r.z), a.z);
    float h  = __fmul_rn(expf_cr(r.w), a.w);
    float x1 = __fdiv_rn(__fsub_rn(cx, __fmul_rn(0.5f, w)), 512.0f);
    float y1 = __fdiv_rn(__fsub_rn(cy, __fmul_rn(0.5f, h)), 512.0f);
    float x2 = __fdiv_rn(__fadd_rn(cx, __fmul_rn(0.5f, w)), 512.0f);
    float y2 = __fdiv_rn(__fadd_rn(cy, __fmul_rn(0.5f, h)), 512.0f);
    x1 = fminf(fmaxf(x1, 0.0f), 1.0f);
    y1 = fminf(fmaxf(y1, 0.0f), 1.0f);
    x2 = fminf(fmaxf(x2, 0.0f), 1.0f);
    y2 = fminf(fmaxf(y2, 0.0f), 1.0f);
    ((float4*)(out + OFF_BOX))[b * K + rank] = make_float4(x1, y1, x2, y2);
    out[OFF_LAB + b * K + rank] = (float)lab;
    float off = __fmul_rn(2.0f, (float)lab);
    boxes_off[b * K + rank] = make_float4(__fadd_rn(x1, off), __fadd_rn(y1, off),
                                          __fadd_rn(x2, off), __fadd_rn(y2, off));
    sel_score[b * K + rank] = score;
}

// Kernel 2: exact top-K via histogram-select + dynamic-N bitonic sort (R8
// config — the R9 rank-scan regressed: O(S^2) LDS broadcasts on a 32-CU grid
// cost 49 µs vs bitonic's ~15). Decode fused in the epilogue.
__global__ void __launch_bounds__(1024)
k_topk(const unsigned long long* __restrict__ keys,
       const int* __restrict__ labels,
       const float* __restrict__ reg, const float* __restrict__ anchors,
       float* __restrict__ out, float4* __restrict__ boxes_off,
       float* __restrict__ sel_score) {
    int b = blockIdx.x;                  // grid = 32
    int tid = threadIdx.x;               // block = 1024
    const unsigned long long* kb = keys + (size_t)b * M;

    __shared__ unsigned int hist[2048];
    __shared__ unsigned int sufA[2048];
    __shared__ unsigned int sufB[2048];
    __shared__ unsigned long long cand[2048];   // 16 KB
    __shared__ int scnt, thrBin, ovf;

    for (int i = tid; i < 2048; i += 1024) hist[i] = 0;
    if (tid == 0) { scnt = 0; ovf = 0; }
    __syncthreads();

    unsigned long long k5[5];
#pragma unroll
    for (int i = 0; i < 5; i++) {
        k5[i] = kb[tid + i * 1024];              // coalesced
        atomicAdd(&hist[(unsigned)(k5[i] >> 51)], 1u);
    }
    __syncthreads();
    // Hillis-Steele suffix scan over 2048 bins (11 steps, ping-pong)
    for (int i = tid; i < 2048; i += 1024) sufA[i] = hist[i];
    __syncthreads();
    unsigned int* src = sufA; unsigned int* dst = sufB;
    for (int d = 1; d < 2048; d <<= 1) {
        for (int i = tid; i < 2048; i += 1024) {
            unsigned int v = src[i];
            if (i + d < 2048) v += src[i + d];
            dst[i] = v;
        }
        __syncthreads();
        unsigned int* tmp = src; src = dst; dst = tmp;
    }
    // threshold bin: unique crossing point of the non-increasing suffix counts
    for (int i = tid; i < 2048; i += 1024) {
        unsigned int s = src[i];
        unsigned int sn = (i + 1 < 2048) ? src[i + 1] : 0u;
        if (s >= (unsigned)K && sn < (unsigned)K) thrBin = i;
    }
    __syncthreads();
    int T = thrBin;
#pragma unroll
    for (int i = 0; i < 5; i++) {
        if ((int)(k5[i] >> 51) >= T) {
            int pos = atomicAdd(&scnt, 1);
            if (pos < 2048) cand[pos] = k5[i]; else ovf = 1;
        }
    }
    __syncthreads();
    if (!ovf) {
        int S = scnt;
        int N = (S <= 1024) ? 1024 : 2048;       // uniform across block
        for (int i = tid; i < 2048; i += 1024)
            if (i >= S) cand[i] = 0ull;          // pad: sorts below real keys
        __syncthreads();
        // bitonic sort, N elems descending (N/2 pairs per stage)
        for (int ksz = 2; ksz <= N; ksz <<= 1) {
            for (int jsz = ksz >> 1; jsz > 0; jsz >>= 1) {
                if (tid < (N >> 1)) {
                    int i = 2 * tid - (tid & (jsz - 1));
                    unsigned long long a = cand[i], c = cand[i + jsz];
                    bool desc = ((i & ksz) == 0);
                    if ((a < c) == desc) { cand[i] = c; cand[i + jsz] = a; }
                }
                __syncthreads();
            }
        }
        if (tid < K) {
            unsigned long long key = cand[tid];
            int mm = (int)(0xFFFFFFFFu - (unsigned)(key & 0xFFFFFFFFu));
            float sc = __uint_as_float((unsigned)(key >> 32));
            int lab = labels[(size_t)b * M + mm];
            decode_write(b, tid, mm, sc, lab, reg, anchors, out, boxes_off, sel_score);
        }
    } else {
        // exact fallback (never expected for this data): O(M) rank per key
#pragma unroll
        for (int i = 0; i < 5; i++) {
            unsigned long long my = k5[i];
            int rank = 0;
            for (int j = 0; j < M; j++) rank += (kb[j] > my) ? 1 : 0;
            if (rank < K) {
                int mm = tid + i * 1024;
                float sc = __uint_as_float((unsigned)(my >> 32));
                int lab = labels[(size_t)b * M + mm];
                decode_write(b, rank, mm, sc, lab, reg, anchors, out, boxes_off, sel_score);
            }
        }
    }
}

// Kernel 3: suppression bitmask, occupancy-tiled + lower-triangle only.
// (word W of row i needed by k_nms iff W <= i>>6 == rowTile; IoU math f32,
// reference op order -> consumed bits bit-identical.)
__global__ void __launch_bounds__(256)
k_mask(const float4* __restrict__ boxes_off,
       unsigned long long* __restrict__ mask) {
    int b = blockIdx.z;
    int rowTile = blockIdx.x;            // 0..15
    int wgGroup = blockIdx.y;            // 0..3
    if (4 * wgGroup > rowTile) return;   // block-uniform: no needed words
    int tid = threadIdx.x;               // 0..255
    __shared__ float4 sbj[256];
    __shared__ float  saj[256];
    __shared__ float4 sbi[64];
    __shared__ float  sai[64];
    int j = wgGroup * 256 + tid;
    float4 bx = (j < K) ? boxes_off[b * K + j]
                        : make_float4(3e30f, 3e30f, -3e30f, -3e30f);
    sbj[tid] = bx;
    saj[tid] = __fmul_rn(__fsub_rn(bx.z, bx.x), __fsub_rn(bx.w, bx.y));
    if (tid < 64) {
        int i = rowTile * 64 + tid;
        float4 bv = (i < K) ? boxes_off[b * K + i] : make_float4(0, 0, 0, 0);
        sbi[tid] = bv;
        sai[tid] = __fmul_rn(__fsub_rn(bv.z, bv.x), __fsub_rn(bv.w, bv.y));
    }
    __syncthreads();
    int r  = tid & 63;                   // row within tile (lane)
    int wg = tid >> 6;                   // word within group (wave index)
    int W  = wgGroup * 4 + wg;           // global word index (wave-uniform)
    if (W > rowTile) return;             // whole-wave exit, after the barrier
    int i = rowTile * 64 + r;
    if (i >= K) return;
    float4 bi = sbi[r];
    float ai = sai[r];
    unsigned long long bits = 0ull;
    int base = wg * 64;
#pragma unroll 8
    for (int jj = 0; jj < 64; jj++) {
        float4 bj = sbj[base + jj];      // wave-uniform -> broadcast
        float xx1 = fmaxf(bi.x, bj.x), yy1 = fmaxf(bi.y, bj.y);
        float xx2 = fminf(bi.z, bj.z), yy2 = fminf(bi.w, bj.w);
        float ww = fmaxf(1e-28f, __fsub_rn(xx2, xx1));
        float hh = fmaxf(1e-28f, __fsub_rn(yy2, yy1));
        float inter = __fmul_rn(ww, hh);
        float denom = __fadd_rn(__fsub_rn(__fadd_rn(ai, saj[base + jj]), inter), 1e-14f);
        float iou = __fdiv_rn(inter, denom);
        if (iou > NMS_T) bits |= (1ull << jj);
    }
    mask[((size_t)b * K + i) * 16 + W] = bits;
}

// Kernel 4: exact NMS via bracketed Jacobi fixed point (see R5 notes).
__global__ void __launch_bounds__(1024)
k_nms(const unsigned long long* __restrict__ mask,
      const float* __restrict__ sel_score,
      float* __restrict__ out) {
    int b = blockIdx.x;
    int j = threadIdx.x;                 // 0..1023
    int w = j >> 6;                      // wave index == keep-word index
    int jb = j & 63;
    __shared__ unsigned long long U[16], L[16];
    __shared__ int flag[2];
    unsigned long long rw[16];
    if (j < K) {
        const ulonglong2* rp2 =
            (const ulonglong2*)(mask + ((size_t)b * K + j) * 16);
#pragma unroll
        for (int t = 0; t < 8; t++) {
            ulonglong2 v = rp2[t];
            rw[2 * t] = v.x; rw[2 * t + 1] = v.y;
        }
#pragma unroll
        for (int t = 0; t < 16; t++) {
            unsigned long long bm =
                (t < w) ? ~0ull
                        : ((t == w && jb != 0) ? ((1ull << jb) - 1ull) : 0ull);
            rw[t] &= bm;                 // only i<j can suppress j
        }
    } else {
#pragma unroll
        for (int t = 0; t < 16; t++) rw[t] = 0ull;
    }
    if (j < 16) { U[j] = (j < 15) ? ~0ull : ((1ull << 40) - 1); L[j] = 0ull; }
    if (j == 0) { flag[0] = 0; flag[1] = 0; }
    __syncthreads();
    for (int k = 0; k < 1025; k++) {
        unsigned long long supU = 0ull, supL = 0ull;
#pragma unroll
        for (int t = 0; t < 16; t++) {
            unsigned long long Ut = U[t], Lt = L[t];   // broadcast (same addr)
            supU |= Lt & rw[t];   // new U = f(L)
            supL |= Ut & rw[t];   // new L = f(U)
        }
        bool nu = (j < K) && (supU == 0ull);
        bool nl = (j < K) && (supL == 0ull);
        __syncthreads();                     // all reads of old U/L done
        unsigned long long bu = __ballot(nu);
        unsigned long long bl = __ballot(nl);
        if (jb == 0) {
            U[w] = bu; L[w] = bl;
            if (bu != bl) flag[k & 1] = 1;
        }
        if (j == 0) flag[(k + 1) & 1] = 0;
        __syncthreads();
        if (flag[k & 1] == 0) break;         // uniform exit; U==L == exact keep
    }
    if (j < K) {
        bool kp = ((U[w] >> jb) & 1ull) != 0ull;
        float s = sel_score[b * K + j];
        kp = kp && (s >= 0.05f);
        out[OFF_SCORE + b * K + j] = kp ? s : 0.0f;
        out[OFF_KEEP + b * K + j]  = kp ? 1.0f : 0.0f;
    }
}

extern "C" void kernel_launch(void* const* d_in, const int* in_sizes, int n_in,
                              void* d_out, int out_size, void* d_ws, size_t ws_size,
                              hipStream_t stream) {
    const float* conf    = (const float*)d_in[0];
    const float* cls     = (const float*)d_in[1];
    const float* reg     = (const float*)d_in[2];
    const float* anchors = (const float*)d_in[3];
    float* out = (float*)d_out;
    char* ws = (char*)d_ws;

    unsigned long long* keys = (unsigned long long*)(ws + WS_KEYS);
    int*    labels   = (int*)(ws + WS_LABELS);
    float*  sel_sc   = (float*)(ws + WS_SELSC);
    float4* boxes_off = (float4*)(ws + WS_BOXOFF);
    unsigned long long* mask = (unsigned long long*)(ws + WS_MASK);

    k_scores<<<dim3(160, B), 256, 0, stream>>>(conf, cls, keys, labels);
    k_topk  <<<B, 1024, 0, stream>>>(keys, labels, reg, anchors, out, boxes_off, sel_sc);
    k_mask  <<<dim3(16, 4, B), 256, 0, stream>>>(boxes_off, mask);
    k_nms   <<<32, 1024, 0, stream>>>(mask, sel_sc, out);
}